// Round 3
// baseline (2743.660 us; speedup 1.0000x reference)
//
#include <hip/hip_runtime.h>
#include <hip/hip_fp16.h>
#include <cstdio>

typedef _Float16 f16;
typedef _Float16 f16x8 __attribute__((ext_vector_type(8)));
typedef _Float16 f16x4 __attribute__((ext_vector_type(4)));
typedef float f32x4 __attribute__((ext_vector_type(4)));

#define DI __device__ __forceinline__

DI void gload_lds16(const void* g, void* l) {
  __builtin_amdgcn_global_load_lds(
      (const __attribute__((address_space(1))) void*)g,
      (__attribute__((address_space(3))) void*)l, 16, 0, 0);
}

// ---------------- cast f32 -> f16, 4 elems/thread ----------------
__global__ void k_cast(const float* __restrict__ in, f16* __restrict__ out, int n4) {
  int i = blockIdx.x * blockDim.x + threadIdx.x;
  if (i >= n4) return;
  float4 v = ((const float4*)in)[i];
  f16x4 o;
  o[0] = (f16)v.x; o[1] = (f16)v.y; o[2] = (f16)v.z; o[3] = (f16)v.w;
  ((f16x4*)out)[i] = o;
}

// ---------------- RoPE in-place on q,k regions of qkv ----------------
// qkv: [16384][3072] fp16. t = token % 8192. angle(t,j) = t * 10000^(-j/512), j in [0,512)
__global__ void k_rope(f16* __restrict__ qkv) {
  int gid = blockIdx.x * blockDim.x + threadIdx.x;  // 16384*512
  int tt = gid >> 9, j = gid & 511;
  int t = tt & 8191;
  float invf = powf(10000.0f, -(float)j * (1.0f / 512.0f));
  float a = (float)t * invf;
  float s, c;
  sincosf(a, &s, &c);
  f16* row = qkv + (size_t)tt * 3072;
  float q0 = (float)row[j], q1 = (float)row[j + 512];
  row[j]       = (f16)(q0 * c - q1 * s);
  row[j + 512] = (f16)(q1 * c + q0 * s);
  float k0 = (float)row[1024 + j], k1 = (float)row[1536 + j];
  row[1024 + j] = (f16)(k0 * c - k1 * s);
  row[1536 + j] = (f16)(k1 * c + k0 * s);
}

// ---------------- V transpose: qkv[:,2048:3072] -> vt[b][d][t] ----------------
__global__ __launch_bounds__(256) void k_transpose(const f16* __restrict__ qkv, f16* __restrict__ vt) {
  __shared__ f16 tile[64][72];
  int bid = blockIdx.x;            // 2 * 128 * 16
  int b = bid >> 11;
  int rem = bid & 2047;
  int tb = (rem >> 4) * 64;        // token base
  int db = (rem & 15) * 64;        // d base
  int tid = threadIdx.x;
  int r = tid >> 2, c0 = (tid & 3) * 16;
  const f16* src = qkv + (size_t)(b * 8192 + tb + r) * 3072 + 2048 + db + c0;
  #pragma unroll
  for (int ii = 0; ii < 16; ++ii) tile[r][c0 + ii] = src[ii];
  __syncthreads();
  f16* dst = vt + (size_t)b * 1024 * 8192 + (size_t)(db + r) * 8192 + tb + c0;
  #pragma unroll
  for (int ii = 0; ii < 16; ++ii) dst[ii] = tile[c0 + ii][r];
}

// ---------------- chunked softmax, IN-PLACE: S row (f32[Kc]) -> P row (f16 at same base)
// chunk c: q rows [c*1024,(c+1)*1024) per batch; Kc=(c+1)*1024.
// Row owned by 16 lanes of one wave. f16 write at byte 2*kk is always below any
// not-yet-read f32 byte 4*kk' (kk'>=kk); kk==0 overlap is read-before-write.
__global__ __launch_bounds__(512)
void k_softmax_c(float* __restrict__ S, int c) {
  int Kc = (c + 1) * 1024;
  int b = blockIdx.x >> 5;
  int rg = blockIdx.x & 31;
  int tid = threadIdx.x;
  int qloc = rg * 32 + (tid >> 4);
  int l16 = tid & 15;
  int qg = c * 1024 + qloc;
  float* Srow = S + (size_t)(b * 1024 + qloc) * Kc;
  float m = -INFINITY, ssum = 0.f;
  for (int kk = l16; kk <= qg; kk += 16) {
    float v = Srow[kk];
    if (v > m) { ssum = ssum * __expf(m - v) + 1.f; m = v; }
    else ssum += __expf(v - m);
  }
  #pragma unroll
  for (int msk = 8; msk >= 1; msk >>= 1) {
    float om = __shfl_xor(m, msk);
    float os = __shfl_xor(ssum, msk);
    float M = fmaxf(m, om);
    float aa = (m > -INFINITY) ? ssum * __expf(m - M) : 0.f;
    float cc = (om > -INFINITY) ? os * __expf(om - M) : 0.f;
    m = M; ssum = aa + cc;
  }
  float rinv = 0.03125f / ssum;  // 1024^-0.5 applied post-softmax (reference quirk)
  int klim = (qg | 127) + 1;     // zero-fill to PV's k-tile boundary
  f16* Prow = (f16*)Srow;
  for (int kk = l16; kk < klim; kk += 16) {
    float v = (kk <= qg) ? Srow[kk] : 0.f;
    asm volatile("" ::: "memory");  // load f32 before aliasing f16 store
    float pv = (kk <= qg) ? __expf(v - m) * rinv : 0.f;
    Prow[kk] = (f16)pv;
  }
}

// ---------------- shared 128x128xK GEMM (all operands K-contig row-major) --------
// MODE 1: qkv = x_h @ w_attn^T + b   (M=16384,N=3072,K=1024) -> fp16
// MODE 2: S[qloc][0:Kc] = q_i @ k^T  (chunk c, causal block skip) -> fp32
// MODE 3: o = P @ vt^T               (chunk c, P in-place in S, lda=2*Kc) -> fp16
// MODE 4: out = o @ w_proj^T + b     (M=16384,N=1024,K=1024) -> fp32
template <int MODE>
__global__ __launch_bounds__(256)
void gemm_k(const f16* __restrict__ A, const f16* __restrict__ B,
            void* __restrict__ C, const float* __restrict__ bias, int c)
{
  __shared__ __align__(16) f16 As[128 * 32];
  __shared__ __align__(16) f16 Bs[128 * 32];

  const int tid = threadIdx.x;
  const int w = tid >> 6;
  const int l = tid & 63;
  const int wm = w >> 1, wn = w & 1;
  const int Kc = (c + 1) * 1024;

  int nk = 0, lda = 0, ldb = 0;
  const f16* Abase = nullptr;
  const f16* Bbase = nullptr;
  size_t crow0 = 0, ccol0 = 0, cld = 0;

  if constexpr (MODE == 1) {
    int bm = blockIdx.x / 24, bn = blockIdx.x % 24;
    Abase = A + (size_t)bm * 128 * 1024; lda = 1024;
    Bbase = B + (size_t)bn * 128 * 1024; ldb = 1024;
    nk = 32; crow0 = (size_t)bm * 128; ccol0 = (size_t)bn * 128; cld = 3072;
  } else if constexpr (MODE == 2) {
    int ncb = (c + 1) * 8;
    int b = blockIdx.x / (8 * ncb);
    int rem = blockIdx.x % (8 * ncb);
    int qb = rem / ncb, jb = rem % ncb;
    if (jb > c * 8 + qb) return;   // fully-masked block (uniform exit, pre-barrier)
    Abase = A + (size_t)(b * 8192 + c * 1024 + qb * 128) * 3072; lda = 3072;
    Bbase = A + (size_t)(b * 8192 + jb * 128) * 3072 + 1024;     ldb = 3072;
    nk = 32;
    crow0 = (size_t)(b * 1024 + qb * 128); ccol0 = (size_t)jb * 128; cld = Kc;
  } else if constexpr (MODE == 3) {
    int b = blockIdx.x / 64;
    int rem = blockIdx.x % 64;
    int qb = rem / 8, nb = rem % 8;
    nk = (c * 8 + qb + 1) * 4;
    Abase = A + (size_t)(b * 1024 + qb * 128) * 2 * Kc; lda = 2 * Kc;  // P in-place
    Bbase = B + (size_t)b * 1024 * 8192 + (size_t)nb * 128 * 8192; ldb = 8192;
    crow0 = (size_t)(b * 8192 + c * 1024 + qb * 128); ccol0 = (size_t)nb * 128; cld = 1024;
  } else {
    int bm = blockIdx.x / 8, bn = blockIdx.x % 8;
    Abase = A + (size_t)bm * 128 * 1024; lda = 1024;
    Bbase = B + (size_t)bn * 128 * 1024; ldb = 1024;
    nk = 32; crow0 = (size_t)bm * 128; ccol0 = (size_t)bn * 128; cld = 1024;
  }

  f32x4 zero = {0.f, 0.f, 0.f, 0.f};
  f32x4 acc[4][4];
  #pragma unroll
  for (int m = 0; m < 4; ++m)
    #pragma unroll
    for (int n = 0; n < 4; ++n) acc[m][n] = zero;

  const int srow = l >> 2;          // staging: 4 lanes per 32-elem row
  const int skoff = (l & 3) * 8;
  const int lr = l & 15;            // fragment row/col
  const int kg = (l >> 4) * 8;      // fragment k offset

  for (int kt = 0; kt < nk; ++kt) {
    const f16* Ak = Abase + (size_t)kt * 32;
    const f16* Bk = Bbase + (size_t)kt * 32;
    #pragma unroll
    for (int s = 0; s < 2; ++s) {
      int rb = s * 64 + w * 16;     // 16 rows per wave per stage
      gload_lds16(Ak + (size_t)(rb + srow) * lda + skoff, &As[rb * 32]);
      gload_lds16(Bk + (size_t)(rb + srow) * ldb + skoff, &Bs[rb * 32]);
    }
    __syncthreads();

    f16x8 av[4], bv[4];
    #pragma unroll
    for (int m = 0; m < 4; ++m) av[m] = *(const f16x8*)&As[(wm * 64 + m * 16 + lr) * 32 + kg];
    #pragma unroll
    for (int n = 0; n < 4; ++n) bv[n] = *(const f16x8*)&Bs[(wn * 64 + n * 16 + lr) * 32 + kg];
    #pragma unroll
    for (int m = 0; m < 4; ++m)
      #pragma unroll
      for (int n = 0; n < 4; ++n)
        acc[m][n] = __builtin_amdgcn_mfma_f32_16x16x32_f16(av[m], bv[n], acc[m][n], 0, 0, 0);
    __syncthreads();
  }

  const int rg = (l >> 4) * 4;  // C/D: col = lane&15, row = (lane>>4)*4 + reg
  #pragma unroll
  for (int m = 0; m < 4; ++m) {
    #pragma unroll
    for (int n = 0; n < 4; ++n) {
      f32x4 v = acc[m][n];
      size_t coll = ccol0 + wn * 64 + n * 16 + lr;
      #pragma unroll
      for (int r = 0; r < 4; ++r) {
        size_t roww = crow0 + wm * 64 + m * 16 + rg + r;
        if constexpr (MODE == 1) {
          ((f16*)C)[roww * cld + coll] = (f16)(v[r] + bias[coll]);
        } else if constexpr (MODE == 2) {
          ((float*)C)[roww * cld + coll] = v[r];
        } else if constexpr (MODE == 3) {
          ((f16*)C)[roww * cld + coll] = (f16)v[r];
        } else {
          ((float*)C)[roww * cld + coll] = v[r] + bias[coll];
        }
      }
    }
  }
}

extern "C" void kernel_launch(void* const* d_in, const int* in_sizes, int n_in,
                              void* d_out, int out_size, void* d_ws, size_t ws_size,
                              hipStream_t stream) {
  (void)in_sizes; (void)n_in;
  const float* x      = (const float*)d_in[0];
  const float* w_attn = (const float*)d_in[1];
  const float* b_attn = (const float*)d_in[2];
  const float* w_proj = (const float*)d_in[3];
  const float* b_proj = (const float*)d_in[4];
  float* out = (float*)d_out;

  const size_t WS_NEED = 243269632ull;  // ~232 MiB, fits the 256 MiB workspace
  if (ws_size < WS_NEED) {
    fprintf(stderr, "kernel_launch: ws_size=%zu < needed %zu -- skipping launches\n",
            ws_size, WS_NEED);
    hipMemsetAsync(d_out, 0, (size_t)out_size * 4, stream);
    return;
  }

  char* p = (char*)d_ws;
  f16* wA_h = (f16*)p; p += (size_t)3072 * 1024 * 2;       //   6.3 MB
  f16* wP_h = (f16*)p; p += (size_t)1024 * 1024 * 2;       //   2.1 MB
  f16* qkv  = (f16*)p; p += (size_t)16384 * 3072 * 2;      // 100.7 MB
  f16* vt   = (f16*)p; p += (size_t)2 * 1024 * 8192 * 2;   //  33.6 MB
  f16* xo   = (f16*)p; p += (size_t)16384 * 1024 * 2;      //  33.6 MB (x_h, then o_h)
  float* S  = (float*)p; p += (size_t)2 * 1024 * 8192 * 4; //  67.1 MB (scores; P in-place)
  // total 243,269,632 bytes

  k_cast<<<16384, 256, 0, stream>>>(x, xo, 4194304);
  k_cast<<<3072, 256, 0, stream>>>(w_attn, wA_h, 786432);
  k_cast<<<1024, 256, 0, stream>>>(w_proj, wP_h, 262144);
  hipLaunchKernelGGL(HIP_KERNEL_NAME(gemm_k<1>), dim3(3072), dim3(256), 0, stream,
                     xo, wA_h, (void*)qkv, b_attn, 0);
  k_rope<<<32768, 256, 0, stream>>>(qkv);
  k_transpose<<<4096, 256, 0, stream>>>(qkv, vt);
  for (int c = 0; c < 8; ++c) {
    hipLaunchKernelGGL(HIP_KERNEL_NAME(gemm_k<2>), dim3(128 * (c + 1)), dim3(256), 0, stream,
                       qkv, (const f16*)nullptr, (void*)S, (const float*)nullptr, c);
    k_softmax_c<<<64, 512, 0, stream>>>(S, c);
    hipLaunchKernelGGL(HIP_KERNEL_NAME(gemm_k<3>), dim3(128), dim3(256), 0, stream,
                       (const f16*)S, vt, (void*)xo, (const float*)nullptr, c);
  }
  hipLaunchKernelGGL(HIP_KERNEL_NAME(gemm_k<4>), dim3(1024), dim3(256), 0, stream,
                     xo, wP_h, (void*)out, b_proj, 0);
}

// Round 4
// 1558.154 us; speedup vs baseline: 1.7608x; 1.7608x over previous
//
#include <hip/hip_runtime.h>
#include <hip/hip_fp16.h>
#include <cstdio>

typedef _Float16 f16;
typedef _Float16 f16x8 __attribute__((ext_vector_type(8)));
typedef _Float16 f16x4 __attribute__((ext_vector_type(4)));
typedef float f32x4 __attribute__((ext_vector_type(4)));

#define DI __device__ __forceinline__

DI void gload_lds16(const void* g, void* l) {
  __builtin_amdgcn_global_load_lds(
      (const __attribute__((address_space(1))) void*)g,
      (__attribute__((address_space(3))) void*)l, 16, 0, 0);
}

// ---------------- cast f32 -> f16, 4 elems/thread ----------------
__global__ void k_cast(const float* __restrict__ in, f16* __restrict__ out, int n4) {
  int i = blockIdx.x * blockDim.x + threadIdx.x;
  if (i >= n4) return;
  float4 v = ((const float4*)in)[i];
  f16x4 o;
  o[0] = (f16)v.x; o[1] = (f16)v.y; o[2] = (f16)v.z; o[3] = (f16)v.w;
  ((f16x4*)out)[i] = o;
}

// ---------------- RoPE in-place on q,k regions of qkv ----------------
__global__ void k_rope(f16* __restrict__ qkv) {
  int gid = blockIdx.x * blockDim.x + threadIdx.x;  // 16384*512
  int tt = gid >> 9, j = gid & 511;
  int t = tt & 8191;
  float invf = powf(10000.0f, -(float)j * (1.0f / 512.0f));
  float a = (float)t * invf;
  float s, c;
  sincosf(a, &s, &c);
  f16* row = qkv + (size_t)tt * 3072;
  float q0 = (float)row[j], q1 = (float)row[j + 512];
  row[j]       = (f16)(q0 * c - q1 * s);
  row[j + 512] = (f16)(q1 * c + q0 * s);
  float k0 = (float)row[1024 + j], k1 = (float)row[1536 + j];
  row[1024 + j] = (f16)(k0 * c - k1 * s);
  row[1536 + j] = (f16)(k1 * c + k0 * s);
}

// ---------------- V transpose: qkv[:,2048:3072] -> vt[b][d][t] ----------------
__global__ __launch_bounds__(256) void k_transpose(const f16* __restrict__ qkv, f16* __restrict__ vt) {
  __shared__ f16 tile[64][72];
  int bid = blockIdx.x;            // 2 * 128 * 16
  int b = bid >> 11;
  int rem = bid & 2047;
  int tb = (rem >> 4) * 64;        // token base
  int db = (rem & 15) * 64;        // d base
  int tid = threadIdx.x;
  int r = tid >> 2, c0 = (tid & 3) * 16;
  const f16* src = qkv + (size_t)(b * 8192 + tb + r) * 3072 + 2048 + db + c0;
  #pragma unroll
  for (int ii = 0; ii < 16; ++ii) tile[r][c0 + ii] = src[ii];
  __syncthreads();
  f16* dst = vt + (size_t)b * 1024 * 8192 + (size_t)(db + r) * 8192 + tb + c0;
  #pragma unroll
  for (int ii = 0; ii < 16; ++ii) dst[ii] = tile[c0 + ii][r];
}

// ---------------- chunked softmax, wave-per-row, float4, IN-PLACE S->P ----------
// chunk c: rows = 2*1024 (b,qloc); Kc=(c+1)*1024; row base S + row*Kc.
// Pass 1: online max+sum, 64 lanes x float4 (1 KiB/wave-load). Pass 2: exp+store
// f16 at same row base (byte 2*kk < byte 4*kk' for unread kk'>=2 -- race-free).
__global__ __launch_bounds__(256)
void k_softmax_c(float* __restrict__ S, int c) {
  int Kc = (c + 1) * 1024;
  int row = blockIdx.x * 4 + (threadIdx.x >> 6);  // 0..2047
  int lane = threadIdx.x & 63;
  int qloc = row & 1023;
  int qg = c * 1024 + qloc;
  float* Srow = S + (size_t)row * Kc;
  int nvalid = qg + 1;

  float m = -INFINITY, ssum = 0.f;
  for (int kk = lane * 4; kk < nvalid; kk += 256) {
    float4 v = *(const float4*)(Srow + kk);
    int rem = nvalid - kk;
    if (rem < 4) {
      if (rem < 2) v.y = -INFINITY;
      if (rem < 3) v.z = -INFINITY;
      v.w = -INFINITY;
    }
    float g = fmaxf(fmaxf(v.x, v.y), fmaxf(v.z, v.w));
    if (g > m) { ssum *= __expf(m - g); m = g; }
    ssum += __expf(v.x - m) + __expf(v.y - m) + __expf(v.z - m) + __expf(v.w - m);
  }
  #pragma unroll
  for (int msk = 32; msk >= 1; msk >>= 1) {
    float om = __shfl_xor(m, msk);
    float os = __shfl_xor(ssum, msk);
    float M = fmaxf(m, om);
    float aa = (m > -INFINITY) ? ssum * __expf(m - M) : 0.f;
    float cc = (om > -INFINITY) ? os * __expf(om - M) : 0.f;
    m = M; ssum = aa + cc;
  }
  float rinv = 0.03125f / ssum;  // 1024^-0.5 applied post-softmax (reference quirk)
  int klim = (qg | 127) + 1;     // zero-fill to PV's k-tile boundary
  f16* Prow = (f16*)Srow;
  for (int kk = lane * 4; kk < klim; kk += 256) {
    float4 v = *(const float4*)(Srow + kk);
    asm volatile("" ::: "memory");  // keep f32 load before aliasing f16 store
    f16x4 o;
    o[0] = (f16)((kk     < nvalid) ? __expf(v.x - m) * rinv : 0.f);
    o[1] = (f16)((kk + 1 < nvalid) ? __expf(v.y - m) * rinv : 0.f);
    o[2] = (f16)((kk + 2 < nvalid) ? __expf(v.z - m) * rinv : 0.f);
    o[3] = (f16)((kk + 3 < nvalid) ? __expf(v.w - m) * rinv : 0.f);
    *(f16x4*)(Prow + kk) = o;
  }
}

// ---------------- shared 128x128xK GEMM (all operands K-contig row-major) --------
// MODE 1: qkv = x_h @ w_attn^T + b   (M=16384,N=3072,K=1024) -> fp16
// MODE 2: S[qloc][0:Kc] = q_i @ k^T  (chunk c, causal block skip) -> fp32
// MODE 3: o = P @ vt^T               (chunk c, P in-place in S, lda=2*Kc) -> fp16
// MODE 4: out = o @ w_proj^T + b     (M=16384,N=1024,K=1024) -> fp32
template <int MODE>
__global__ __launch_bounds__(256)
void gemm_k(const f16* __restrict__ A, const f16* __restrict__ B,
            void* __restrict__ C, const float* __restrict__ bias, int c)
{
  __shared__ __align__(16) f16 As[128 * 32];
  __shared__ __align__(16) f16 Bs[128 * 32];

  const int tid = threadIdx.x;
  const int w = tid >> 6;
  const int l = tid & 63;
  const int wm = w >> 1, wn = w & 1;
  const int Kc = (c + 1) * 1024;

  int nk = 0, lda = 0, ldb = 0;
  const f16* Abase = nullptr;
  const f16* Bbase = nullptr;
  size_t crow0 = 0, ccol0 = 0, cld = 0;

  if constexpr (MODE == 1) {
    int bm = blockIdx.x / 24, bn = blockIdx.x % 24;
    Abase = A + (size_t)bm * 128 * 1024; lda = 1024;
    Bbase = B + (size_t)bn * 128 * 1024; ldb = 1024;
    nk = 32; crow0 = (size_t)bm * 128; ccol0 = (size_t)bn * 128; cld = 3072;
  } else if constexpr (MODE == 2) {
    int ncb = (c + 1) * 8;
    int b = blockIdx.x / (8 * ncb);
    int rem = blockIdx.x % (8 * ncb);
    int qb = rem / ncb, jb = rem % ncb;
    if (jb > c * 8 + qb) return;   // fully-masked block (uniform exit, pre-barrier)
    Abase = A + (size_t)(b * 8192 + c * 1024 + qb * 128) * 3072; lda = 3072;
    Bbase = A + (size_t)(b * 8192 + jb * 128) * 3072 + 1024;     ldb = 3072;
    nk = 32;
    crow0 = (size_t)(b * 1024 + qb * 128); ccol0 = (size_t)jb * 128; cld = Kc;
  } else if constexpr (MODE == 3) {
    int b = blockIdx.x / 64;
    int rem = blockIdx.x % 64;
    int qb = rem / 8, nb = rem % 8;
    nk = (c * 8 + qb + 1) * 4;
    Abase = A + (size_t)(b * 1024 + qb * 128) * 2 * Kc; lda = 2 * Kc;  // P in-place
    Bbase = B + (size_t)b * 1024 * 8192 + (size_t)nb * 128 * 8192; ldb = 8192;
    crow0 = (size_t)(b * 8192 + c * 1024 + qb * 128); ccol0 = (size_t)nb * 128; cld = 1024;
  } else {
    int bm = blockIdx.x / 8, bn = blockIdx.x % 8;
    Abase = A + (size_t)bm * 128 * 1024; lda = 1024;
    Bbase = B + (size_t)bn * 128 * 1024; ldb = 1024;
    nk = 32; crow0 = (size_t)bm * 128; ccol0 = (size_t)bn * 128; cld = 1024;
  }

  f32x4 zero = {0.f, 0.f, 0.f, 0.f};
  f32x4 acc[4][4];
  #pragma unroll
  for (int m = 0; m < 4; ++m)
    #pragma unroll
    for (int n = 0; n < 4; ++n) acc[m][n] = zero;

  const int srow = l >> 2;          // staging: 4 lanes per 32-elem row
  const int skoff = (l & 3) * 8;
  const int lr = l & 15;            // fragment row/col
  const int kg = (l >> 4) * 8;      // fragment k offset

  for (int kt = 0; kt < nk; ++kt) {
    const f16* Ak = Abase + (size_t)kt * 32;
    const f16* Bk = Bbase + (size_t)kt * 32;
    #pragma unroll
    for (int s = 0; s < 2; ++s) {
      int rb = s * 64 + w * 16;     // 16 rows per wave per stage
      gload_lds16(Ak + (size_t)(rb + srow) * lda + skoff, &As[rb * 32]);
      gload_lds16(Bk + (size_t)(rb + srow) * ldb + skoff, &Bs[rb * 32]);
    }
    __syncthreads();

    f16x8 av[4], bv[4];
    #pragma unroll
    for (int m = 0; m < 4; ++m) av[m] = *(const f16x8*)&As[(wm * 64 + m * 16 + lr) * 32 + kg];
    #pragma unroll
    for (int n = 0; n < 4; ++n) bv[n] = *(const f16x8*)&Bs[(wn * 64 + n * 16 + lr) * 32 + kg];
    #pragma unroll
    for (int m = 0; m < 4; ++m)
      #pragma unroll
      for (int n = 0; n < 4; ++n)
        acc[m][n] = __builtin_amdgcn_mfma_f32_16x16x32_f16(av[m], bv[n], acc[m][n], 0, 0, 0);
    __syncthreads();
  }

  const int rg = (l >> 4) * 4;  // C/D: col = lane&15, row = (lane>>4)*4 + reg
  #pragma unroll
  for (int m = 0; m < 4; ++m) {
    #pragma unroll
    for (int n = 0; n < 4; ++n) {
      f32x4 v = acc[m][n];
      size_t coll = ccol0 + wn * 64 + n * 16 + lr;
      #pragma unroll
      for (int r = 0; r < 4; ++r) {
        size_t roww = crow0 + wm * 64 + m * 16 + rg + r;
        if constexpr (MODE == 1) {
          ((f16*)C)[roww * cld + coll] = (f16)(v[r] + bias[coll]);
        } else if constexpr (MODE == 2) {
          ((float*)C)[roww * cld + coll] = v[r];
        } else if constexpr (MODE == 3) {
          ((f16*)C)[roww * cld + coll] = (f16)v[r];
        } else {
          ((float*)C)[roww * cld + coll] = v[r] + bias[coll];
        }
      }
    }
  }
}

extern "C" void kernel_launch(void* const* d_in, const int* in_sizes, int n_in,
                              void* d_out, int out_size, void* d_ws, size_t ws_size,
                              hipStream_t stream) {
  (void)in_sizes; (void)n_in;
  const float* x      = (const float*)d_in[0];
  const float* w_attn = (const float*)d_in[1];
  const float* b_attn = (const float*)d_in[2];
  const float* w_proj = (const float*)d_in[3];
  const float* b_proj = (const float*)d_in[4];
  float* out = (float*)d_out;

  const size_t WS_NEED = 243269632ull;  // ~232 MiB, fits the 256 MiB workspace
  if (ws_size < WS_NEED) {
    fprintf(stderr, "kernel_launch: ws_size=%zu < needed %zu -- skipping launches\n",
            ws_size, WS_NEED);
    hipMemsetAsync(d_out, 0, (size_t)out_size * 4, stream);
    return;
  }

  char* p = (char*)d_ws;
  f16* wA_h = (f16*)p; p += (size_t)3072 * 1024 * 2;       //   6.3 MB
  f16* wP_h = (f16*)p; p += (size_t)1024 * 1024 * 2;       //   2.1 MB
  f16* qkv  = (f16*)p; p += (size_t)16384 * 3072 * 2;      // 100.7 MB
  f16* vt   = (f16*)p; p += (size_t)2 * 1024 * 8192 * 2;   //  33.6 MB
  f16* xo   = (f16*)p; p += (size_t)16384 * 1024 * 2;      //  33.6 MB (x_h, then o_h)
  float* S  = (float*)p; p += (size_t)2 * 1024 * 8192 * 4; //  67.1 MB (scores; P in-place)
  // total 243,269,632 bytes

  k_cast<<<16384, 256, 0, stream>>>(x, xo, 4194304);
  k_cast<<<3072, 256, 0, stream>>>(w_attn, wA_h, 786432);
  k_cast<<<1024, 256, 0, stream>>>(w_proj, wP_h, 262144);
  hipLaunchKernelGGL(HIP_KERNEL_NAME(gemm_k<1>), dim3(3072), dim3(256), 0, stream,
                     xo, wA_h, (void*)qkv, b_attn, 0);
  k_rope<<<32768, 256, 0, stream>>>(qkv);
  k_transpose<<<4096, 256, 0, stream>>>(qkv, vt);
  for (int c = 0; c < 8; ++c) {
    hipLaunchKernelGGL(HIP_KERNEL_NAME(gemm_k<2>), dim3(128 * (c + 1)), dim3(256), 0, stream,
                       qkv, (const f16*)nullptr, (void*)S, (const float*)nullptr, c);
    k_softmax_c<<<512, 256, 0, stream>>>(S, c);
    hipLaunchKernelGGL(HIP_KERNEL_NAME(gemm_k<3>), dim3(128), dim3(256), 0, stream,
                       (const f16*)S, vt, (void*)xo, (const float*)nullptr, c);
  }
  hipLaunchKernelGGL(HIP_KERNEL_NAME(gemm_k<4>), dim3(1024), dim3(256), 0, stream,
                     xo, wP_h, (void*)out, b_proj, 0);
}

// Round 6
// 1150.506 us; speedup vs baseline: 2.3847x; 1.3543x over previous
//
#include <hip/hip_runtime.h>
#include <hip/hip_fp16.h>
#include <cstdio>

typedef _Float16 f16;
typedef _Float16 f16x8 __attribute__((ext_vector_type(8)));
typedef _Float16 f16x4 __attribute__((ext_vector_type(4)));
typedef float f32x4 __attribute__((ext_vector_type(4)));

#define DI __device__ __forceinline__

DI void gload_lds16(const void* g, void* l) {
  __builtin_amdgcn_global_load_lds(
      (const __attribute__((address_space(1))) void*)g,
      (__attribute__((address_space(3))) void*)l, 16, 0, 0);
}

// ---------------- zero f32 buffer, 4 elems/thread ----------------
__global__ void k_zero(float* __restrict__ buf) {
  int i = blockIdx.x * blockDim.x + threadIdx.x;
  f32x4 z = {0.f, 0.f, 0.f, 0.f};
  ((f32x4*)buf)[i] = z;
}

// ---------------- cast f32 -> f16, 4 elems/thread ----------------
__global__ void k_cast(const float* __restrict__ in, f16* __restrict__ out, int n4) {
  int i = blockIdx.x * blockDim.x + threadIdx.x;
  if (i >= n4) return;
  float4 v = ((const float4*)in)[i];
  f16x4 o;
  o[0] = (f16)v.x; o[1] = (f16)v.y; o[2] = (f16)v.z; o[3] = (f16)v.w;
  ((f16x4*)out)[i] = o;
}

// ---------------- O32 (f32 split-K accum) -> xo rows of chunk c ----------------
__global__ void k_o_cast(const float* __restrict__ O32, f16* __restrict__ xo, int c) {
  int i = blockIdx.x * blockDim.x + threadIdx.x;  // over 2*1024*1024/4
  int b = i >> 18;
  int loc = i & 262143;                            // (row in chunk)*256 + col4
  float4 v = ((const float4*)O32)[i];
  f16x4 o;
  o[0] = (f16)v.x; o[1] = (f16)v.y; o[2] = (f16)v.z; o[3] = (f16)v.w;
  ((f16x4*)(xo + (size_t)(b * 8192 + c * 1024) * 1024))[loc] = o;
}

// ---------------- RoPE in-place on q,k regions of qkv ----------------
__global__ void k_rope(f16* __restrict__ qkv) {
  int gid = blockIdx.x * blockDim.x + threadIdx.x;  // 16384*512
  int tt = gid >> 9, j = gid & 511;
  int t = tt & 8191;
  float invf = powf(10000.0f, -(float)j * (1.0f / 512.0f));
  float a = (float)t * invf;
  float s, c;
  sincosf(a, &s, &c);
  f16* row = qkv + (size_t)tt * 3072;
  float q0 = (float)row[j], q1 = (float)row[j + 512];
  row[j]       = (f16)(q0 * c - q1 * s);
  row[j + 512] = (f16)(q1 * c + q0 * s);
  float k0 = (float)row[1024 + j], k1 = (float)row[1536 + j];
  row[1024 + j] = (f16)(k0 * c - k1 * s);
  row[1536 + j] = (f16)(k1 * c + k0 * s);
}

// ---------------- V transpose: qkv[:,2048:3072] -> vt[b][d][t] ----------------
__global__ __launch_bounds__(256) void k_transpose(const f16* __restrict__ qkv, f16* __restrict__ vt) {
  __shared__ f16 tile[64][72];
  int bid = blockIdx.x;            // 2 * 128 * 16
  int b = bid >> 11;
  int rem = bid & 2047;
  int tb = (rem >> 4) * 64;        // token base
  int db = (rem & 15) * 64;        // d base
  int tid = threadIdx.x;
  int r = tid >> 2, c0 = (tid & 3) * 16;
  const f16* src = qkv + (size_t)(b * 8192 + tb + r) * 3072 + 2048 + db + c0;
  #pragma unroll
  for (int ii = 0; ii < 16; ++ii) tile[r][c0 + ii] = src[ii];
  __syncthreads();
  f16* dst = vt + (size_t)b * 1024 * 8192 + (size_t)(db + r) * 8192 + tb + c0;
  #pragma unroll
  for (int ii = 0; ii < 16; ++ii) dst[ii] = tile[c0 + ii][r];
}

// ---------------- chunked softmax, wave-per-row, float4, IN-PLACE S->P ----------
__global__ __launch_bounds__(256)
void k_softmax_c(float* __restrict__ S, int c) {
  int Kc = (c + 1) * 1024;
  int row = blockIdx.x * 4 + (threadIdx.x >> 6);  // 0..2047
  int lane = threadIdx.x & 63;
  int qloc = row & 1023;
  int qg = c * 1024 + qloc;
  float* Srow = S + (size_t)row * Kc;
  int nvalid = qg + 1;

  float m = -INFINITY, ssum = 0.f;
  for (int kk = lane * 4; kk < nvalid; kk += 256) {
    float4 v = *(const float4*)(Srow + kk);
    int rem = nvalid - kk;
    if (rem < 4) {
      if (rem < 2) v.y = -INFINITY;
      if (rem < 3) v.z = -INFINITY;
      v.w = -INFINITY;
    }
    float g = fmaxf(fmaxf(v.x, v.y), fmaxf(v.z, v.w));
    if (g > m) { ssum *= __expf(m - g); m = g; }
    ssum += __expf(v.x - m) + __expf(v.y - m) + __expf(v.z - m) + __expf(v.w - m);
  }
  #pragma unroll
  for (int msk = 32; msk >= 1; msk >>= 1) {
    float om = __shfl_xor(m, msk);
    float os = __shfl_xor(ssum, msk);
    float M = fmaxf(m, om);
    float aa = (m > -INFINITY) ? ssum * __expf(m - M) : 0.f;
    float cc = (om > -INFINITY) ? os * __expf(om - M) : 0.f;
    m = M; ssum = aa + cc;
  }
  float rinv = 0.03125f / ssum;  // 1024^-0.5 applied post-softmax (reference quirk)
  int klim = (qg | 127) + 1;     // zero-fill to PV's k-tile boundary
  f16* Prow = (f16*)Srow;
  for (int kk = lane * 4; kk < klim; kk += 256) {
    float4 v = *(const float4*)(Srow + kk);
    asm volatile("" ::: "memory");  // keep f32 load before aliasing f16 store
    f16x4 o;
    o[0] = (f16)((kk     < nvalid) ? __expf(v.x - m) * rinv : 0.f);
    o[1] = (f16)((kk + 1 < nvalid) ? __expf(v.y - m) * rinv : 0.f);
    o[2] = (f16)((kk + 2 < nvalid) ? __expf(v.z - m) * rinv : 0.f);
    o[3] = (f16)((kk + 3 < nvalid) ? __expf(v.w - m) * rinv : 0.f);
    *(f16x4*)(Prow + kk) = o;
  }
}

// ---------------- shared 128x128xK GEMM, 2-phase double-buffered LDS --------------
// MODE 1: qkv = x_h @ w_attn^T + b   -> fp16
// MODE 2: S[qloc][0:Kc] = q_i @ k^T  (chunk c, causal block skip) -> fp32
// MODE 3: O32 += P @ vt^T  (chunk c, split-K x2, f32 atomic accumulate)
// MODE 4: out = o @ w_proj^T + b     -> fp32
template <int MODE>
__global__ __launch_bounds__(256)
void gemm_k(const f16* __restrict__ A, const f16* __restrict__ B,
            void* __restrict__ C, const float* __restrict__ bias, int c)
{
  __shared__ __align__(16) f16 As[2][128 * 32];
  __shared__ __align__(16) f16 Bs[2][128 * 32];

  const int tid = threadIdx.x;
  const int w = tid >> 6;
  const int l = tid & 63;
  const int wm = w >> 1, wn = w & 1;
  const int Kc = (c + 1) * 1024;

  int k0 = 0, k1 = 0, lda = 0, ldb = 0;
  const f16* Abase = nullptr;
  const f16* Bbase = nullptr;
  size_t crow0 = 0, ccol0 = 0, cld = 0;

  if constexpr (MODE == 1) {
    int bm = blockIdx.x / 24, bn = blockIdx.x % 24;
    Abase = A + (size_t)bm * 128 * 1024; lda = 1024;
    Bbase = B + (size_t)bn * 128 * 1024; ldb = 1024;
    k1 = 32; crow0 = (size_t)bm * 128; ccol0 = (size_t)bn * 128; cld = 3072;
  } else if constexpr (MODE == 2) {
    int ncb = (c + 1) * 8;
    int b = blockIdx.x / (8 * ncb);
    int rem = blockIdx.x % (8 * ncb);
    int qb = rem / ncb, jb = rem % ncb;
    if (jb > c * 8 + qb) return;   // fully-masked block (uniform exit, pre-barrier)
    Abase = A + (size_t)(b * 8192 + c * 1024 + qb * 128) * 3072; lda = 3072;
    Bbase = A + (size_t)(b * 8192 + jb * 128) * 3072 + 1024;     ldb = 3072;
    k1 = 32;
    crow0 = (size_t)(b * 1024 + qb * 128); ccol0 = (size_t)jb * 128; cld = Kc;
  } else if constexpr (MODE == 3) {
    int s = blockIdx.x & 1;
    int rem = blockIdx.x >> 1;     // 2*8*8
    int b = rem / 64; rem %= 64;
    int qb = rem / 8, nb = rem % 8;
    int nkt = c * 8 + qb + 1;      // k-tiles of 128 tokens
    int half = (nkt + 1) >> 1;
    int t0 = s ? half : 0;
    int t1 = s ? nkt : half;
    if (t0 >= t1) return;          // uniform exit
    k0 = t0 * 4; k1 = t1 * 4;      // K-steps of 32
    Abase = A + (size_t)(b * 1024 + qb * 128) * 2 * Kc; lda = 2 * Kc;  // P in-place
    Bbase = B + (size_t)b * 1024 * 8192 + (size_t)nb * 128 * 8192; ldb = 8192;
    crow0 = (size_t)(b * 1024 + qb * 128); ccol0 = (size_t)nb * 128; cld = 1024;
  } else {
    int bm = blockIdx.x / 8, bn = blockIdx.x % 8;
    Abase = A + (size_t)bm * 128 * 1024; lda = 1024;
    Bbase = B + (size_t)bn * 128 * 1024; ldb = 1024;
    k1 = 32; crow0 = (size_t)bm * 128; ccol0 = (size_t)bn * 128; cld = 1024;
  }

  f32x4 zero = {0.f, 0.f, 0.f, 0.f};
  f32x4 acc[4][4];
  #pragma unroll
  for (int m = 0; m < 4; ++m)
    #pragma unroll
    for (int n = 0; n < 4; ++n) acc[m][n] = zero;

  const int srow = l >> 2;          // staging: 4 lanes per 32-elem row
  const int skoff = (l & 3) * 8;
  const int lr = l & 15;            // fragment row/col
  const int kg = (l >> 4) * 8;      // fragment k offset

  // ---- prologue: stage k0 into buf 0 ----
  {
    const f16* Ak = Abase + (size_t)k0 * 32;
    const f16* Bk = Bbase + (size_t)k0 * 32;
    #pragma unroll
    for (int s = 0; s < 2; ++s) {
      int rb = s * 64 + w * 16;
      gload_lds16(Ak + (size_t)(rb + srow) * lda + skoff, &As[0][rb * 32]);
      gload_lds16(Bk + (size_t)(rb + srow) * ldb + skoff, &Bs[0][rb * 32]);
    }
  }
  __syncthreads();

  for (int kt = k0; kt < k1; ++kt) {
    int cur = (kt - k0) & 1;
    if (kt + 1 < k1) {              // issue next-tile loads BEFORE compute
      const f16* Ak = Abase + (size_t)(kt + 1) * 32;
      const f16* Bk = Bbase + (size_t)(kt + 1) * 32;
      #pragma unroll
      for (int s = 0; s < 2; ++s) {
        int rb = s * 64 + w * 16;
        gload_lds16(Ak + (size_t)(rb + srow) * lda + skoff, &As[cur ^ 1][rb * 32]);
        gload_lds16(Bk + (size_t)(rb + srow) * ldb + skoff, &Bs[cur ^ 1][rb * 32]);
      }
    }
    f16x8 av[4], bv[4];
    #pragma unroll
    for (int m = 0; m < 4; ++m) av[m] = *(const f16x8*)&As[cur][(wm * 64 + m * 16 + lr) * 32 + kg];
    #pragma unroll
    for (int n = 0; n < 4; ++n) bv[n] = *(const f16x8*)&Bs[cur][(wn * 64 + n * 16 + lr) * 32 + kg];
    #pragma unroll
    for (int m = 0; m < 4; ++m)
      #pragma unroll
      for (int n = 0; n < 4; ++n)
        acc[m][n] = __builtin_amdgcn_mfma_f32_16x16x32_f16(av[m], bv[n], acc[m][n], 0, 0, 0);
    __syncthreads();                // drains vmcnt(0): next buf ready, cur buf free
  }

  const int rg = (l >> 4) * 4;  // C/D: col = lane&15, row = (lane>>4)*4 + reg
  #pragma unroll
  for (int m = 0; m < 4; ++m) {
    #pragma unroll
    for (int n = 0; n < 4; ++n) {
      f32x4 v = acc[m][n];
      size_t coll = ccol0 + wn * 64 + n * 16 + lr;
      #pragma unroll
      for (int r = 0; r < 4; ++r) {
        size_t roww = crow0 + wm * 64 + m * 16 + rg + r;
        if constexpr (MODE == 1) {
          ((f16*)C)[roww * cld + coll] = (f16)(v[r] + bias[coll]);
        } else if constexpr (MODE == 2) {
          ((float*)C)[roww * cld + coll] = v[r];
        } else if constexpr (MODE == 3) {
          atomicAdd(&((float*)C)[roww * cld + coll], v[r]);
        } else {
          ((float*)C)[roww * cld + coll] = v[r] + bias[coll];
        }
      }
    }
  }
}

extern "C" void kernel_launch(void* const* d_in, const int* in_sizes, int n_in,
                              void* d_out, int out_size, void* d_ws, size_t ws_size,
                              hipStream_t stream) {
  (void)in_sizes; (void)n_in;
  const float* x      = (const float*)d_in[0];
  const float* w_attn = (const float*)d_in[1];
  const float* b_attn = (const float*)d_in[2];
  const float* w_proj = (const float*)d_in[3];
  const float* b_proj = (const float*)d_in[4];
  float* out = (float*)d_out;

  const size_t WS_NEED = 251658240ull;  // 240 MiB
  if (ws_size < WS_NEED) {
    fprintf(stderr, "kernel_launch: ws_size=%zu < needed %zu -- skipping launches\n",
            ws_size, WS_NEED);
    hipMemsetAsync(d_out, 0, (size_t)out_size * 4, stream);
    return;
  }

  char* p = (char*)d_ws;
  f16* wA_h = (f16*)p; p += (size_t)3072 * 1024 * 2;       //   6.3 MB
  f16* wP_h = (f16*)p; p += (size_t)1024 * 1024 * 2;       //   2.1 MB
  f16* qkv  = (f16*)p; p += (size_t)16384 * 3072 * 2;      // 100.7 MB
  f16* vt   = (f16*)p; p += (size_t)2 * 1024 * 8192 * 2;   //  33.6 MB
  f16* xo   = (f16*)p; p += (size_t)16384 * 1024 * 2;      //  33.6 MB (x_h, then o_h)
  float* O32= (float*)p; p += (size_t)2 * 1024 * 1024 * 4; //   8.4 MB (split-K accum)
  float* S  = (float*)p; p += (size_t)2 * 1024 * 8192 * 4; //  67.1 MB (scores; P in-place)
  // total 251,658,240 bytes

  k_cast<<<16384, 256, 0, stream>>>(x, xo, 4194304);
  k_cast<<<3072, 256, 0, stream>>>(w_attn, wA_h, 786432);
  k_cast<<<1024, 256, 0, stream>>>(w_proj, wP_h, 262144);
  hipLaunchKernelGGL(HIP_KERNEL_NAME(gemm_k<1>), dim3(3072), dim3(256), 0, stream,
                     xo, wA_h, (void*)qkv, b_attn, 0);
  k_rope<<<32768, 256, 0, stream>>>(qkv);
  k_transpose<<<4096, 256, 0, stream>>>(qkv, vt);
  for (int c = 0; c < 8; ++c) {
    hipLaunchKernelGGL(HIP_KERNEL_NAME(gemm_k<2>), dim3(128 * (c + 1)), dim3(256), 0, stream,
                       qkv, (const f16*)nullptr, (void*)S, (const float*)nullptr, c);
    k_softmax_c<<<512, 256, 0, stream>>>(S, c);
    k_zero<<<2048, 256, 0, stream>>>(O32);
    hipLaunchKernelGGL(HIP_KERNEL_NAME(gemm_k<3>), dim3(256), dim3(256), 0, stream,
                       (const f16*)S, vt, (void*)O32, (const float*)nullptr, c);
    k_o_cast<<<2048, 256, 0, stream>>>(O32, xo, c);
  }
  hipLaunchKernelGGL(HIP_KERNEL_NAME(gemm_k<4>), dim3(1024), dim3(256), 0, stream,
                     xo, wP_h, (void*)out, b_proj, 0);
}

// Round 9
// 1119.058 us; speedup vs baseline: 2.4518x; 1.0281x over previous
//
#include <hip/hip_runtime.h>
#include <hip/hip_fp16.h>
#include <cstdio>

typedef _Float16 f16;
typedef _Float16 f16x8 __attribute__((ext_vector_type(8)));
typedef _Float16 f16x4 __attribute__((ext_vector_type(4)));
typedef float f32x4 __attribute__((ext_vector_type(4)));

#define DI __device__ __forceinline__

DI void gload_lds16(const void* g, void* l) {
  __builtin_amdgcn_global_load_lds(
      (const __attribute__((address_space(1))) void*)g,
      (__attribute__((address_space(3))) void*)l, 16, 0, 0);
}

// XCD-aware block swizzle (bijective when gridDim.x % 8 == 0) [T1]
DI int xcd_swz() {
  int nwg = gridDim.x, bid = blockIdx.x;
  if ((nwg & 7) == 0) bid = (bid & 7) * (nwg >> 3) + (bid >> 3);
  return bid;
}

// ---------------- cast f32 -> f16, 4 elems/thread ----------------
__global__ void k_cast(const float* __restrict__ in, f16* __restrict__ out, int n4) {
  int i = blockIdx.x * blockDim.x + threadIdx.x;
  if (i >= n4) return;
  float4 v = ((const float4*)in)[i];
  f16x4 o;
  o[0] = (f16)v.x; o[1] = (f16)v.y; o[2] = (f16)v.z; o[3] = (f16)v.w;
  ((f16x4*)out)[i] = o;
}

// ---------------- RoPE in-place on q,k regions of qkv ----------------
__global__ void k_rope(f16* __restrict__ qkv) {
  int gid = blockIdx.x * blockDim.x + threadIdx.x;  // 16384*512
  int tt = gid >> 9, j = gid & 511;
  int t = tt & 8191;
  float invf = powf(10000.0f, -(float)j * (1.0f / 512.0f));
  float a = (float)t * invf;
  float s, c;
  sincosf(a, &s, &c);
  f16* row = qkv + (size_t)tt * 3072;
  float q0 = (float)row[j], q1 = (float)row[j + 512];
  row[j]       = (f16)(q0 * c - q1 * s);
  row[j + 512] = (f16)(q1 * c + q0 * s);
  float k0 = (float)row[1024 + j], k1 = (float)row[1536 + j];
  row[1024 + j] = (f16)(k0 * c - k1 * s);
  row[1536 + j] = (f16)(k1 * c + k0 * s);
}

// ---------------- V transpose: qkv[:,2048:3072] -> vt[b][d][t] ----------------
__global__ __launch_bounds__(256) void k_transpose(const f16* __restrict__ qkv, f16* __restrict__ vt) {
  __shared__ f16 tile[64][72];
  int bid = blockIdx.x;            // 2 * 128 * 16
  int b = bid >> 11;
  int rem = bid & 2047;
  int tb = (rem >> 4) * 64;        // token base
  int db = (rem & 15) * 64;        // d base
  int tid = threadIdx.x;
  int r = tid >> 2, c0 = (tid & 3) * 16;
  const f16* src = qkv + (size_t)(b * 8192 + tb + r) * 3072 + 2048 + db + c0;
  #pragma unroll
  for (int ii = 0; ii < 16; ++ii) tile[r][c0 + ii] = src[ii];
  __syncthreads();
  f16* dst = vt + (size_t)b * 1024 * 8192 + (size_t)(db + r) * 8192 + tb + c0;
  #pragma unroll
  for (int ii = 0; ii < 16; ++ii) dst[ii] = tile[c0 + ii][r];
}

// ---------------- chunk softmax, wave-per-row, float4, IN-PLACE S->P ----------
// chunk [q0,q1): R = q1-q0 rows per batch; S is [2R][q1] f32, batch stride R rows.
__global__ __launch_bounds__(256)
void k_softmax_c(float* __restrict__ S, int q0, int q1) {
  int R = q1 - q0;
  int row = blockIdx.x * 4 + (threadIdx.x >> 6);  // 0..2R-1
  int lane = threadIdx.x & 63;
  int b = (row >= R) ? 1 : 0;
  int qloc = row - b * R;
  int qg = q0 + qloc;
  float* Srow = S + (size_t)row * q1;
  int nvalid = qg + 1;

  float m = -INFINITY, ssum = 0.f;
  for (int kk = lane * 4; kk < nvalid; kk += 256) {
    float4 v = *(const float4*)(Srow + kk);
    int rem = nvalid - kk;
    if (rem < 4) {
      if (rem < 2) v.y = -INFINITY;
      if (rem < 3) v.z = -INFINITY;
      v.w = -INFINITY;
    }
    float g = fmaxf(fmaxf(v.x, v.y), fmaxf(v.z, v.w));
    if (g > m) { ssum *= __expf(m - g); m = g; }
    ssum += __expf(v.x - m) + __expf(v.y - m) + __expf(v.z - m) + __expf(v.w - m);
  }
  #pragma unroll
  for (int msk = 32; msk >= 1; msk >>= 1) {
    float om = __shfl_xor(m, msk);
    float os = __shfl_xor(ssum, msk);
    float M = fmaxf(m, om);
    float aa = (m > -INFINITY) ? ssum * __expf(m - M) : 0.f;
    float cc = (om > -INFINITY) ? os * __expf(om - M) : 0.f;
    m = M; ssum = aa + cc;
  }
  float rinv = 0.03125f / ssum;  // 1024^-0.5 applied post-softmax (reference quirk)
  int klim = (qg | 127) + 1;     // zero-fill to PV's k-tile boundary
  f16* Prow = (f16*)Srow;
  for (int kk = lane * 4; kk < klim; kk += 256) {
    float4 v = *(const float4*)(Srow + kk);
    asm volatile("" ::: "memory");  // keep f32 load before aliasing f16 store
    f16x4 o;
    o[0] = (f16)((kk     < nvalid) ? __expf(v.x - m) * rinv : 0.f);
    o[1] = (f16)((kk + 1 < nvalid) ? __expf(v.y - m) * rinv : 0.f);
    o[2] = (f16)((kk + 2 < nvalid) ? __expf(v.z - m) * rinv : 0.f);
    o[3] = (f16)((kk + 3 < nvalid) ? __expf(v.w - m) * rinv : 0.f);
    *(f16x4*)(Prow + kk) = o;
  }
}

// ---------------- shared 128x128xK GEMM, 2-phase double-buffered LDS --------------
// MODE 1: qkv = x_h @ w_attn^T + b   -> fp16
// MODE 2: S[2R][q1] = q @ k^T        (chunk [q0,q1), causal block skip) -> fp32
// MODE 3: xo = P @ vt^T              (chunk, P in-place in S, lda=2*q1) -> fp16
// MODE 4: out = o @ w_proj^T + b     -> fp32
template <int MODE>
__global__ __launch_bounds__(256)
void gemm_k(const f16* __restrict__ A, const f16* __restrict__ B,
            void* __restrict__ C, const float* __restrict__ bias, int q0, int q1)
{
  __shared__ __align__(16) f16 As[2][128 * 32];
  __shared__ __align__(16) f16 Bs[2][128 * 32];

  const int tid = threadIdx.x;
  const int w = tid >> 6;
  const int l = tid & 63;
  const int wm = w >> 1, wn = w & 1;
  const int bid = xcd_swz();
  const int R = q1 - q0;

  int k0 = 0, k1 = 0, lda = 0, ldb = 0;
  const f16* Abase = nullptr;
  const f16* Bbase = nullptr;
  size_t crow0 = 0, ccol0 = 0, cld = 0;

  if constexpr (MODE == 1) {
    int bm = bid / 24, bn = bid % 24;
    Abase = A + (size_t)bm * 128 * 1024; lda = 1024;
    Bbase = B + (size_t)bn * 128 * 1024; ldb = 1024;
    k1 = 32; crow0 = (size_t)bm * 128; ccol0 = (size_t)bn * 128; cld = 3072;
  } else if constexpr (MODE == 2) {
    int nqt = R >> 7, ncb = q1 >> 7;
    int b = bid / (nqt * ncb);
    int rem = bid % (nqt * ncb);
    int qb = rem / ncb, jb = rem % ncb;
    if (jb > (q0 >> 7) + qb) return;   // fully-masked block (uniform exit, pre-barrier)
    Abase = A + (size_t)(b * 8192 + q0 + qb * 128) * 3072; lda = 3072;
    Bbase = A + (size_t)(b * 8192 + jb * 128) * 3072 + 1024; ldb = 3072;
    k1 = 32;
    crow0 = (size_t)(b * R + qb * 128); ccol0 = (size_t)jb * 128; cld = q1;
  } else if constexpr (MODE == 3) {
    int nqt = R >> 7;
    int b = bid / (nqt * 8);
    int rem = bid % (nqt * 8);
    int qb = rem / 8, nb = rem % 8;
    k1 = ((q0 >> 7) + qb + 1) * 4;     // K-steps of 32 over valid k-tiles
    Abase = A + (size_t)(b * R + qb * 128) * 2 * q1; lda = 2 * q1;  // P in-place
    Bbase = B + (size_t)b * 1024 * 8192 + (size_t)nb * 128 * 8192; ldb = 8192;
    crow0 = (size_t)(b * 8192 + q0 + qb * 128); ccol0 = (size_t)nb * 128; cld = 1024;
  } else {
    int bm = bid / 8, bn = bid % 8;
    Abase = A + (size_t)bm * 128 * 1024; lda = 1024;
    Bbase = B + (size_t)bn * 128 * 1024; ldb = 1024;
    k1 = 32; crow0 = (size_t)bm * 128; ccol0 = (size_t)bn * 128; cld = 1024;
  }

  f32x4 zero = {0.f, 0.f, 0.f, 0.f};
  f32x4 acc[4][4];
  #pragma unroll
  for (int m = 0; m < 4; ++m)
    #pragma unroll
    for (int n = 0; n < 4; ++n) acc[m][n] = zero;

  const int srow = l >> 2;          // staging: 4 lanes per 32-elem row
  const int skoff = (l & 3) * 8;
  const int lr = l & 15;            // fragment row/col
  const int kg = (l >> 4) * 8;      // fragment k offset

  // ---- prologue: stage k0 into buf 0 ----
  {
    const f16* Ak = Abase + (size_t)k0 * 32;
    const f16* Bk = Bbase + (size_t)k0 * 32;
    #pragma unroll
    for (int s = 0; s < 2; ++s) {
      int rb = s * 64 + w * 16;
      gload_lds16(Ak + (size_t)(rb + srow) * lda + skoff, &As[0][rb * 32]);
      gload_lds16(Bk + (size_t)(rb + srow) * ldb + skoff, &Bs[0][rb * 32]);
    }
  }
  __syncthreads();

  for (int kt = k0; kt < k1; ++kt) {
    int cur = (kt - k0) & 1;
    if (kt + 1 < k1) {              // issue next-tile loads BEFORE compute
      const f16* Ak = Abase + (size_t)(kt + 1) * 32;
      const f16* Bk = Bbase + (size_t)(kt + 1) * 32;
      #pragma unroll
      for (int s = 0; s < 2; ++s) {
        int rb = s * 64 + w * 16;
        gload_lds16(Ak + (size_t)(rb + srow) * lda + skoff, &As[cur ^ 1][rb * 32]);
        gload_lds16(Bk + (size_t)(rb + srow) * ldb + skoff, &Bs[cur ^ 1][rb * 32]);
      }
    }
    f16x8 av[4], bv[4];
    #pragma unroll
    for (int m = 0; m < 4; ++m) av[m] = *(const f16x8*)&As[cur][(wm * 64 + m * 16 + lr) * 32 + kg];
    #pragma unroll
    for (int n = 0; n < 4; ++n) bv[n] = *(const f16x8*)&Bs[cur][(wn * 64 + n * 16 + lr) * 32 + kg];
    #pragma unroll
    for (int m = 0; m < 4; ++m)
      #pragma unroll
      for (int n = 0; n < 4; ++n)
        acc[m][n] = __builtin_amdgcn_mfma_f32_16x16x32_f16(av[m], bv[n], acc[m][n], 0, 0, 0);
    __syncthreads();                // drains vmcnt(0): next buf ready, cur buf free
  }

  const int rg = (l >> 4) * 4;  // C/D: col = lane&15, row = (lane>>4)*4 + reg
  #pragma unroll
  for (int m = 0; m < 4; ++m) {
    #pragma unroll
    for (int n = 0; n < 4; ++n) {
      f32x4 v = acc[m][n];
      size_t coll = ccol0 + wn * 64 + n * 16 + lr;
      #pragma unroll
      for (int r = 0; r < 4; ++r) {
        size_t roww = crow0 + wm * 64 + m * 16 + rg + r;
        if constexpr (MODE == 1) {
          ((f16*)C)[roww * cld + coll] = (f16)(v[r] + bias[coll]);
        } else if constexpr (MODE == 2) {
          ((float*)C)[roww * cld + coll] = v[r];
        } else if constexpr (MODE == 3) {
          ((f16*)C)[roww * cld + coll] = (f16)v[r];
        } else {
          ((float*)C)[roww * cld + coll] = v[r] + bias[coll];
        }
      }
    }
  }
}

extern "C" void kernel_launch(void* const* d_in, const int* in_sizes, int n_in,
                              void* d_out, int out_size, void* d_ws, size_t ws_size,
                              hipStream_t stream) {
  (void)in_sizes; (void)n_in;
  const float* x      = (const float*)d_in[0];
  const float* w_attn = (const float*)d_in[1];
  const float* b_attn = (const float*)d_in[2];
  const float* w_proj = (const float*)d_in[3];
  const float* b_proj = (const float*)d_in[4];
  float* out = (float*)d_out;

  const size_t WS_NEED = 264765440ull;  // 252.5 MiB
  if (ws_size < WS_NEED) {
    fprintf(stderr, "kernel_launch: ws_size=%zu < needed %zu -- skipping launches\n",
            ws_size, WS_NEED);
    hipMemsetAsync(d_out, 0, (size_t)out_size * 4, stream);
    return;
  }

  char* p = (char*)d_ws;
  f16* wA_h = (f16*)p; p += (size_t)3072 * 1024 * 2;       //   6.3 MB
  f16* wP_h = (f16*)p; p += (size_t)1024 * 1024 * 2;       //   2.1 MB
  f16* qkv  = (f16*)p; p += (size_t)16384 * 3072 * 2;      // 100.7 MB
  f16* vt   = (f16*)p; p += (size_t)2 * 1024 * 8192 * 2;   //  33.6 MB
  f16* xo   = (f16*)p; p += (size_t)16384 * 1024 * 2;      //  33.6 MB (x_h, then o_h)
  float* S  = (float*)p; p += (size_t)2 * 3328 * 3328 * 4; //  88.6 MB (scores; P in-place)
  // total 264,765,440 bytes

  k_cast<<<16384, 256, 0, stream>>>(x, xo, 4194304);
  k_cast<<<3072, 256, 0, stream>>>(w_attn, wA_h, 786432);
  k_cast<<<1024, 256, 0, stream>>>(w_proj, wP_h, 262144);
  hipLaunchKernelGGL(HIP_KERNEL_NAME(gemm_k<1>), dim3(3072), dim3(256), 0, stream,
                     xo, wA_h, (void*)qkv, b_attn, 0, 8192);
  k_rope<<<32768, 256, 0, stream>>>(qkv);
  k_transpose<<<4096, 256, 0, stream>>>(qkv, vt);

  // 4 variable chunks equalizing S footprint: grids stay large (no split-K needed)
  const int Q0[4] = {0, 3328, 5376, 6912};
  const int Q1[4] = {3328, 5376, 6912, 8192};
  for (int c = 0; c < 4; ++c) {
    int q0 = Q0[c], q1 = Q1[c], R = q1 - q0;
    int nqt = R >> 7, ncb = q1 >> 7;
    hipLaunchKernelGGL(HIP_KERNEL_NAME(gemm_k<2>), dim3(2 * nqt * ncb), dim3(256), 0, stream,
                       qkv, (const f16*)nullptr, (void*)S, (const float*)nullptr, q0, q1);
    k_softmax_c<<<R / 2, 256, 0, stream>>>(S, q0, q1);
    hipLaunchKernelGGL(HIP_KERNEL_NAME(gemm_k<3>), dim3(2 * nqt * 8), dim3(256), 0, stream,
                       (const f16*)S, vt, (void*)xo, (const float*)nullptr, q0, q1);
  }
  hipLaunchKernelGGL(HIP_KERNEL_NAME(gemm_k<4>), dim3(1024), dim3(256), 0, stream,
                     xo, wP_h, (void*)out, b_proj, 0, 8192);
}

// Round 10
// 1035.330 us; speedup vs baseline: 2.6500x; 1.0809x over previous
//
#include <hip/hip_runtime.h>
#include <hip/hip_fp16.h>
#include <cstdio>

typedef _Float16 f16;
typedef _Float16 f16x8 __attribute__((ext_vector_type(8)));
typedef _Float16 f16x4 __attribute__((ext_vector_type(4)));
typedef float f32x4 __attribute__((ext_vector_type(4)));

#define DI __device__ __forceinline__

DI void gload_lds16(const void* g, void* l) {
  __builtin_amdgcn_global_load_lds(
      (const __attribute__((address_space(1))) void*)g,
      (__attribute__((address_space(3))) void*)l, 16, 0, 0);
}

// XCD-aware block swizzle (bijective when gridDim.x % 8 == 0) [T1]
DI int xcd_swz() {
  int nwg = gridDim.x, bid = blockIdx.x;
  if ((nwg & 7) == 0) bid = (bid & 7) * (nwg >> 3) + (bid >> 3);
  return bid;
}

// ---------------- cast f32 -> f16, 4 elems/thread ----------------
__global__ void k_cast(const float* __restrict__ in, f16* __restrict__ out, int n4) {
  int i = blockIdx.x * blockDim.x + threadIdx.x;
  if (i >= n4) return;
  float4 v = ((const float4*)in)[i];
  f16x4 o;
  o[0] = (f16)v.x; o[1] = (f16)v.y; o[2] = (f16)v.z; o[3] = (f16)v.w;
  ((f16x4*)out)[i] = o;
}

// ---------------- RoPE in-place on q,k regions of qkv ----------------
__global__ void k_rope(f16* __restrict__ qkv) {
  int gid = blockIdx.x * blockDim.x + threadIdx.x;  // 16384*512
  int tt = gid >> 9, j = gid & 511;
  int t = tt & 8191;
  float invf = powf(10000.0f, -(float)j * (1.0f / 512.0f));
  float a = (float)t * invf;
  float s, c;
  sincosf(a, &s, &c);
  f16* row = qkv + (size_t)tt * 3072;
  float q0 = (float)row[j], q1 = (float)row[j + 512];
  row[j]       = (f16)(q0 * c - q1 * s);
  row[j + 512] = (f16)(q1 * c + q0 * s);
  float k0 = (float)row[1024 + j], k1 = (float)row[1536 + j];
  row[1024 + j] = (f16)(k0 * c - k1 * s);
  row[1536 + j] = (f16)(k1 * c + k0 * s);
}

// ---------------- V transpose: qkv[:,2048:3072] -> vt[b][d][t] ----------------
__global__ __launch_bounds__(256) void k_transpose(const f16* __restrict__ qkv, f16* __restrict__ vt) {
  __shared__ f16 tile[64][72];
  int bid = blockIdx.x;            // 2 * 128 * 16
  int b = bid >> 11;
  int rem = bid & 2047;
  int tb = (rem >> 4) * 64;        // token base
  int db = (rem & 15) * 64;        // d base
  int tid = threadIdx.x;
  int r = tid >> 2, c0 = (tid & 3) * 16;
  const f16* src = qkv + (size_t)(b * 8192 + tb + r) * 3072 + 2048 + db + c0;
  #pragma unroll
  for (int ii = 0; ii < 16; ++ii) tile[r][c0 + ii] = src[ii];
  __syncthreads();
  f16* dst = vt + (size_t)b * 1024 * 8192 + (size_t)(db + r) * 8192 + tb + c0;
  #pragma unroll
  for (int ii = 0; ii < 16; ++ii) dst[ii] = tile[c0 + ii][r];
}

// ---------------- chunk softmax, wave-per-row, float4, IN-PLACE S->P ----------
// chunk [q0,q1): R = q1-q0 rows per batch; S is [2R][q1] f32, batch stride R rows.
__global__ __launch_bounds__(256)
void k_softmax_c(float* __restrict__ S, int q0, int q1) {
  int R = q1 - q0;
  int row = blockIdx.x * 4 + (threadIdx.x >> 6);  // 0..2R-1
  int lane = threadIdx.x & 63;
  int b = (row >= R) ? 1 : 0;
  int qloc = row - b * R;
  int qg = q0 + qloc;
  float* Srow = S + (size_t)row * q1;
  int nvalid = qg + 1;

  float m = -INFINITY, ssum = 0.f;
  for (int kk = lane * 4; kk < nvalid; kk += 256) {
    float4 v = *(const float4*)(Srow + kk);
    int rem = nvalid - kk;
    if (rem < 4) {
      if (rem < 2) v.y = -INFINITY;
      if (rem < 3) v.z = -INFINITY;
      v.w = -INFINITY;
    }
    float g = fmaxf(fmaxf(v.x, v.y), fmaxf(v.z, v.w));
    if (g > m) { ssum *= __expf(m - g); m = g; }
    ssum += __expf(v.x - m) + __expf(v.y - m) + __expf(v.z - m) + __expf(v.w - m);
  }
  #pragma unroll
  for (int msk = 32; msk >= 1; msk >>= 1) {
    float om = __shfl_xor(m, msk);
    float os = __shfl_xor(ssum, msk);
    float M = fmaxf(m, om);
    float aa = (m > -INFINITY) ? ssum * __expf(m - M) : 0.f;
    float cc = (om > -INFINITY) ? os * __expf(om - M) : 0.f;
    m = M; ssum = aa + cc;
  }
  float rinv = 0.03125f / ssum;  // 1024^-0.5 applied post-softmax (reference quirk)
  int klim = (qg | 127) + 1;     // zero-fill to PV's k-tile boundary
  f16* Prow = (f16*)Srow;
  for (int kk = lane * 4; kk < klim; kk += 256) {
    float4 v = *(const float4*)(Srow + kk);
    asm volatile("" ::: "memory");  // keep f32 load before aliasing f16 store
    f16x4 o;
    o[0] = (f16)((kk     < nvalid) ? __expf(v.x - m) * rinv : 0.f);
    o[1] = (f16)((kk + 1 < nvalid) ? __expf(v.y - m) * rinv : 0.f);
    o[2] = (f16)((kk + 2 < nvalid) ? __expf(v.z - m) * rinv : 0.f);
    o[3] = (f16)((kk + 3 < nvalid) ? __expf(v.w - m) * rinv : 0.f);
    *(f16x4*)(Prow + kk) = o;
  }
}

// ---------------- shared 128x128xK GEMM, 2-phase dbuf, hoisted pointers ----------
// MODE 1: qkv = x_h @ w_attn^T + b   -> fp16
// MODE 2: S[2R][q1] = q @ k^T        (chunk [q0,q1), causal block skip) -> fp32
// MODE 3: xo = P @ vt^T              (chunk, P in-place in S, lda=2*q1) -> fp16
// MODE 4: out = o @ w_proj^T + b     -> fp32
template <int MODE>
__global__ __launch_bounds__(256)
void gemm_k(const f16* __restrict__ A, const f16* __restrict__ B,
            void* __restrict__ C, const float* __restrict__ bias, int q0, int q1)
{
  // four separate buffers: ping/pong selection is fully compile-time
  __shared__ __align__(16) f16 As0[128 * 32];
  __shared__ __align__(16) f16 As1[128 * 32];
  __shared__ __align__(16) f16 Bs0[128 * 32];
  __shared__ __align__(16) f16 Bs1[128 * 32];

  const int tid = threadIdx.x;
  const int w = tid >> 6;
  const int l = tid & 63;
  const int wm = w >> 1, wn = w & 1;
  const int bid = xcd_swz();
  const int R = q1 - q0;

  int nk = 0;
  const f16* Abase = nullptr;
  const f16* Bbase = nullptr;
  size_t crow0 = 0, ccol0 = 0, cld = 0;
  // compile-time strides where possible
  const int LDA = (MODE == 2) ? 3072 : (MODE == 3 ? 2 * q1 : 1024);
  const int LDB = (MODE == 2) ? 3072 : (MODE == 3 ? 8192 : 1024);

  if constexpr (MODE == 1) {
    int bm = bid / 24, bn = bid % 24;
    Abase = A + (size_t)bm * 128 * 1024;
    Bbase = B + (size_t)bn * 128 * 1024;
    nk = 32; crow0 = (size_t)bm * 128; ccol0 = (size_t)bn * 128; cld = 3072;
  } else if constexpr (MODE == 2) {
    int nqt = R >> 7, ncb = q1 >> 7;
    int b = bid / (nqt * ncb);
    int rem = bid % (nqt * ncb);
    int qb = rem / ncb, jb = rem % ncb;
    if (jb > (q0 >> 7) + qb) return;   // fully-masked block (uniform exit, pre-barrier)
    Abase = A + (size_t)(b * 8192 + q0 + qb * 128) * 3072;
    Bbase = A + (size_t)(b * 8192 + jb * 128) * 3072 + 1024;
    nk = 32;
    crow0 = (size_t)(b * R + qb * 128); ccol0 = (size_t)jb * 128; cld = q1;
  } else if constexpr (MODE == 3) {
    int nqt = R >> 7;
    int b = bid / (nqt * 8);
    int rem = bid % (nqt * 8);
    int qb = rem / 8, nb = rem % 8;
    nk = ((q0 >> 7) + qb + 1) * 4;     // K-steps of 32 over valid k-tiles (even)
    Abase = A + (size_t)(b * R + qb * 128) * 2 * q1;   // P in-place in S
    Bbase = B + (size_t)b * 1024 * 8192 + (size_t)nb * 128 * 8192;
    crow0 = (size_t)(b * 8192 + q0 + qb * 128); ccol0 = (size_t)nb * 128; cld = 1024;
  } else {
    int bm = bid / 8, bn = bid % 8;
    Abase = A + (size_t)bm * 128 * 1024;
    Bbase = B + (size_t)bn * 128 * 1024;
    nk = 32; crow0 = (size_t)bm * 128; ccol0 = (size_t)bn * 128; cld = 1024;
  }

  f32x4 zero = {0.f, 0.f, 0.f, 0.f};
  f32x4 acc[4][4];
  #pragma unroll
  for (int m = 0; m < 4; ++m)
    #pragma unroll
    for (int n = 0; n < 4; ++n) acc[m][n] = zero;

  const int srow = l >> 2;          // staging: 4 lanes per 32-elem row
  const int skoff = (l & 3) * 8;
  const int lr = l & 15;            // fragment row/col
  const int kg = (l >> 4) * 8;      // fragment k offset
  const int rb0 = w * 16;           // stage rows, s=0
  const int rb1 = 64 + w * 16;      // stage rows, s=1

  // hoisted per-lane global staging pointers (advance by +32 elems per K-step)
  const f16* gA0 = Abase + (size_t)(rb0 + srow) * LDA + skoff;
  const f16* gA1 = Abase + (size_t)(rb1 + srow) * LDA + skoff;
  const f16* gB0 = Bbase + (size_t)(rb0 + srow) * LDB + skoff;
  const f16* gB1 = Bbase + (size_t)(rb1 + srow) * LDB + skoff;

  // hoisted LDS fragment-read bases (reads use immediate offsets m*64 f16x8)
  const f16x8* rA0 = (const f16x8*)&As0[(wm * 64 + lr) * 32 + kg];
  const f16x8* rA1 = (const f16x8*)&As1[(wm * 64 + lr) * 32 + kg];
  const f16x8* rB0 = (const f16x8*)&Bs0[(wn * 64 + lr) * 32 + kg];
  const f16x8* rB1 = (const f16x8*)&Bs1[(wn * 64 + lr) * 32 + kg];

#define STAGE0() do { \
    gload_lds16(gA0, &As0[rb0 * 32]); gload_lds16(gA1, &As0[rb1 * 32]); \
    gload_lds16(gB0, &Bs0[rb0 * 32]); gload_lds16(gB1, &Bs0[rb1 * 32]); } while (0)
#define STAGE1() do { \
    gload_lds16(gA0, &As1[rb0 * 32]); gload_lds16(gA1, &As1[rb1 * 32]); \
    gload_lds16(gB0, &Bs1[rb0 * 32]); gload_lds16(gB1, &Bs1[rb1 * 32]); } while (0)
#define ADV() do { gA0 += 32; gA1 += 32; gB0 += 32; gB1 += 32; } while (0)
#define COMPUTE(rA, rB) do { \
    f16x8 av[4], bv[4]; \
    _Pragma("unroll") for (int m = 0; m < 4; ++m) av[m] = (rA)[m * 64]; \
    _Pragma("unroll") for (int n = 0; n < 4; ++n) bv[n] = (rB)[n * 64]; \
    _Pragma("unroll") for (int m = 0; m < 4; ++m) \
      _Pragma("unroll") for (int n = 0; n < 4; ++n) \
        acc[m][n] = __builtin_amdgcn_mfma_f32_16x16x32_f16(av[m], bv[n], acc[m][n], 0, 0, 0); \
  } while (0)

  // prologue: stage tile 0 into buf0
  STAGE0(); ADV();
  __syncthreads();

  // nk is even for all modes; ping/pong unrolled x2, no toggle arithmetic
  for (int it = 0; it + 2 <= nk; it += 2) {
    STAGE1(); ADV();              // stage tile it+1 (issued before compute)
    COMPUTE(rA0, rB0);            // compute tile it
    __syncthreads();
    if (it + 2 < nk) { STAGE0(); }  // stage tile it+2
    ADV();
    COMPUTE(rA1, rB1);            // compute tile it+1
    __syncthreads();
  }
#undef STAGE0
#undef STAGE1
#undef ADV
#undef COMPUTE

  const int rg = (l >> 4) * 4;  // C/D: col = lane&15, row = (lane>>4)*4 + reg
  #pragma unroll
  for (int m = 0; m < 4; ++m) {
    #pragma unroll
    for (int n = 0; n < 4; ++n) {
      f32x4 v = acc[m][n];
      size_t coll = ccol0 + wn * 64 + n * 16 + lr;
      #pragma unroll
      for (int r = 0; r < 4; ++r) {
        size_t roww = crow0 + wm * 64 + m * 16 + rg + r;
        if constexpr (MODE == 1) {
          ((f16*)C)[roww * cld + coll] = (f16)(v[r] + bias[coll]);
        } else if constexpr (MODE == 2) {
          ((float*)C)[roww * cld + coll] = v[r];
        } else if constexpr (MODE == 3) {
          ((f16*)C)[roww * cld + coll] = (f16)v[r];
        } else {
          ((float*)C)[roww * cld + coll] = v[r] + bias[coll];
        }
      }
    }
  }
}

extern "C" void kernel_launch(void* const* d_in, const int* in_sizes, int n_in,
                              void* d_out, int out_size, void* d_ws, size_t ws_size,
                              hipStream_t stream) {
  (void)in_sizes; (void)n_in;
  const float* x      = (const float*)d_in[0];
  const float* w_attn = (const float*)d_in[1];
  const float* b_attn = (const float*)d_in[2];
  const float* w_proj = (const float*)d_in[3];
  const float* b_proj = (const float*)d_in[4];
  float* out = (float*)d_out;

  const size_t WS_NEED = 264765440ull;  // 252.5 MiB
  if (ws_size < WS_NEED) {
    fprintf(stderr, "kernel_launch: ws_size=%zu < needed %zu -- skipping launches\n",
            ws_size, WS_NEED);
    hipMemsetAsync(d_out, 0, (size_t)out_size * 4, stream);
    return;
  }

  char* p = (char*)d_ws;
  f16* wA_h = (f16*)p; p += (size_t)3072 * 1024 * 2;       //   6.3 MB
  f16* wP_h = (f16*)p; p += (size_t)1024 * 1024 * 2;       //   2.1 MB
  f16* qkv  = (f16*)p; p += (size_t)16384 * 3072 * 2;      // 100.7 MB
  f16* vt   = (f16*)p; p += (size_t)2 * 1024 * 8192 * 2;   //  33.6 MB
  f16* xo   = (f16*)p; p += (size_t)16384 * 1024 * 2;      //  33.6 MB (x_h, then o_h)
  float* S  = (float*)p; p += (size_t)2 * 3328 * 3328 * 4; //  88.6 MB (scores; P in-place)
  // total 264,765,440 bytes

  k_cast<<<16384, 256, 0, stream>>>(x, xo, 4194304);
  k_cast<<<3072, 256, 0, stream>>>(w_attn, wA_h, 786432);
  k_cast<<<1024, 256, 0, stream>>>(w_proj, wP_h, 262144);
  hipLaunchKernelGGL(HIP_KERNEL_NAME(gemm_k<1>), dim3(3072), dim3(256), 0, stream,
                     xo, wA_h, (void*)qkv, b_attn, 0, 8192);
  k_rope<<<32768, 256, 0, stream>>>(qkv);
  k_transpose<<<4096, 256, 0, stream>>>(qkv, vt);

  // 4 variable chunks equalizing S footprint: grids stay large (no split-K needed)
  const int Q0[4] = {0, 3328, 5376, 6912};
  const int Q1[4] = {3328, 5376, 6912, 8192};
  for (int c = 0; c < 4; ++c) {
    int q0 = Q0[c], q1 = Q1[c], R = q1 - q0;
    int nqt = R >> 7, ncb = q1 >> 7;
    hipLaunchKernelGGL(HIP_KERNEL_NAME(gemm_k<2>), dim3(2 * nqt * ncb), dim3(256), 0, stream,
                       qkv, (const f16*)nullptr, (void*)S, (const float*)nullptr, q0, q1);
    k_softmax_c<<<R / 2, 256, 0, stream>>>(S, q0, q1);
    hipLaunchKernelGGL(HIP_KERNEL_NAME(gemm_k<3>), dim3(2 * nqt * 8), dim3(256), 0, stream,
                       (const f16*)S, vt, (void*)xo, (const float*)nullptr, q0, q1);
  }
  hipLaunchKernelGGL(HIP_KERNEL_NAME(gemm_k<4>), dim3(1024), dim3(256), 0, stream,
                     xo, wP_h, (void*)out, b_proj, 0, 8192);
}